// Round 5
// baseline (391.065 us; speedup 1.0000x reference)
//
#include <hip/hip_runtime.h>
#include <hip/hip_bf16.h>
#include <float.h>
#include <math.h>

typedef __hip_bfloat16 bf16;
typedef __attribute__((ext_vector_type(8))) short short8;
typedef __attribute__((ext_vector_type(4))) float f32x4;

__device__ __forceinline__ float bf2f(bf16 v){ return __bfloat162float(v); }
__device__ __forceinline__ void stv(float* p, float v){ *p = v; }
__device__ __forceinline__ void stv(bf16* p, float v){ *p = __float2bfloat16(v); }
__device__ __forceinline__ float nanfix(float v){
  if (v != v) return 0.f;
  return fminf(fmaxf(v, -FLT_MAX), FLT_MAX);
}
__device__ __forceinline__ unsigned short f2bu(float f){
  unsigned u = __float_as_uint(f);
  unsigned r = u + 0x7FFFu + ((u>>16)&1u);
  return (unsigned short)(r>>16);
}
template<int VEC>
__device__ __forceinline__ void ldbf(const bf16* p, float (&o)[VEC]){
  if constexpr (VEC==4){
    ushort4 r = *(const ushort4*)p;
    o[0]=__uint_as_float((unsigned)r.x<<16); o[1]=__uint_as_float((unsigned)r.y<<16);
    o[2]=__uint_as_float((unsigned)r.z<<16); o[3]=__uint_as_float((unsigned)r.w<<16);
  } else {
    ushort2 r = *(const ushort2*)p;
    o[0]=__uint_as_float((unsigned)r.x<<16); o[1]=__uint_as_float((unsigned)r.y<<16);
  }
}

// async global->LDS, 16B per lane. LDS dest must be wave-uniform base + lane*16.
__device__ __forceinline__ void gl_lds16(const bf16* g, bf16* l){
  __builtin_amdgcn_global_load_lds(
      (const __attribute__((address_space(1))) void*)g,
      (__attribute__((address_space(3))) void*)l, 16, 0, 0);
}

// bijective XCD-chunk remap (m204): consecutive original ids round-robin across
// XCDs; remap so each XCD owns a CONTIGUOUS chunk of (bx,by) space -> j-neighbor
// blocks (sharing an A row-panel) land on the same XCD's L2.
__device__ __forceinline__ void xcd_remap(int gx, int total, int &bx, int &by){
  int orig = by*gx + bx;
  int q8 = total >> 3, r8 = total & 7;
  int xcd = orig & 7, rest = orig >> 3;
  int nid = (xcd < r8) ? (xcd*(q8+1) + rest)
                       : (r8*(q8+1) + (xcd-r8)*q8 + rest);
  bx = nid % gx; by = nid / gx;
}

// ---------------- parallel scan + scatter (deg lives in k_setup) ----------------
__global__ void k_scan1(const int* __restrict__ deg, int* __restrict__ bsum, int N){
  __shared__ int sm[256];
  int i = blockIdx.x*256 + threadIdx.x;
  sm[threadIdx.x] = (i < N) ? deg[i] : 0;
  __syncthreads();
  for (int off = 128; off > 0; off >>= 1){
    if (threadIdx.x < off) sm[threadIdx.x] += sm[threadIdx.x + off];
    __syncthreads();
  }
  if (threadIdx.x == 0) bsum[blockIdx.x] = sm[0];
}

__global__ void k_scan2(int* __restrict__ bsum, int NB){
  __shared__ int sm[1024];
  int tid = threadIdx.x;
  sm[tid] = (tid < NB) ? bsum[tid] : 0;
  __syncthreads();
  for (int off = 1; off < 1024; off <<= 1){
    int t = (tid >= off) ? sm[tid-off] : 0;
    __syncthreads();
    sm[tid] += t;
    __syncthreads();
  }
  if (tid < NB) bsum[tid] = (tid == 0) ? 0 : sm[tid-1];   // exclusive block offsets
}

__global__ void k_scan3(const int* __restrict__ deg, const int* __restrict__ bsum,
                        int* __restrict__ offs, int N){
  __shared__ int sm[256];
  int tid = threadIdx.x;
  int i = blockIdx.x*256 + tid;
  int v = (i < N) ? deg[i] : 0;
  sm[tid] = v; __syncthreads();
  for (int off = 1; off < 256; off <<= 1){
    int t = (tid >= off) ? sm[tid-off] : 0;
    __syncthreads();
    sm[tid] += t;
    __syncthreads();
  }
  if (i < N) offs[i+1] = bsum[blockIdx.x] + sm[tid];
  if (i == 0) offs[0] = 0;
}

__global__ void k_scatter(const int* __restrict__ src, const int* __restrict__ tgt,
                          const int* __restrict__ offs, int* __restrict__ cnt,
                          int* __restrict__ ssrc, int E){
  int e = blockIdx.x*blockDim.x + threadIdx.x;
  if (e < E){
    int t = tgt[e];
    int pos = offs[t] + atomicAdd(&cnt[t], 1);
    ssrc[pos] = src[e];
  }
}

// ---------------- fused setup: weight repacks + x conversion + degree count ----------------
__device__ __forceinline__ void rp_pqT(const float* preW, const float* preB,
                                       bf16* WpqT, float* bpq, int K, int F, int idx){
  int NC = 4*F;
  int total = 2*NC*K;
  if (idx < total){
    int j = idx/K, c = idx%K;
    int half = j/NC, jj = j%NC, t = jj/F, f = jj%F;
    WpqT[idx] = __float2bfloat16(preW[(t*2*K + half*K + c)*F + f]);
  }
  if (idx < 2*NC) bpq[idx] = (idx < NC) ? preB[idx] : 0.f;
}
__device__ __forceinline__ void rp_xT(const float* postW, const float* postB,
                                      bf16* WxT, float* bpost, int KX, int F, int idx){
  int NC = 4*F; int KP = KX + 12*F;
  if (idx < NC*KX){
    int j = idx/KX, c = idx%KX, t = j/F, f = j%F;
    WxT[idx] = __float2bfloat16(postW[(t*KP + c)*F + f]);
  }
  if (idx < NC) bpost[idx] = postB[idx];
}
__device__ __forceinline__ void rp_agg3(const float* postW, bf16* Wagg3,
                                        int KX, int F, int idx){
  int K4F = 4*F; int KP = KX + 12*F;
  int total = 4*3*F*K4F;
  if (idx < total){
    int k = idx % K4F; int r = idx / K4F;
    int zr = r % (3*F); int t = r / (3*F);
    int s = zr / F, f = zr % F;
    Wagg3[idx] = __float2bfloat16(postW[((size_t)(t*KP + KX + s*K4F + k))*F + f]);
  }
}
__device__ __forceinline__ void rp_linT(const float* linW, bf16* WlinT,
                                        int K, int NC, int idx){
  if (idx < NC*K){
    int j = idx/K, c = idx%K;
    WlinT[idx] = __float2bfloat16(linW[c*NC + j]);
  }
}

struct SetupArgs {
  const float *pre1W, *pre1b, *post1W, *post1b, *lin1W;
  const float *pre2W, *pre2b, *post2W, *post2b, *lin2W;
  const float *x;
  const int *tgt;
  bf16 *WpqT1, *WxT1, *Wagg31, *lin1WT;
  bf16 *WpqT2, *WxT2, *Wagg32, *lin2WT;
  bf16 *x_bf;
  int *deg;
  float *bpq1, *bpost1, *bpq2, *bpost2;
  int nx4;       // N*IN/4
  int E;
  int gstride;   // gridDim.x*256
};

__global__ void k_setup(SetupArgs a){
  int idx = blockIdx.x*256 + threadIdx.x;
  switch (blockIdx.y){
    case 0: rp_pqT (a.pre1W, a.pre1b, a.WpqT1, a.bpq1, 128, 64, idx); break;
    case 1: rp_xT  (a.post1W, a.post1b, a.WxT1, a.bpost1, 128, 64, idx); break;
    case 2: rp_agg3(a.post1W, a.Wagg31, 128, 64, idx); break;
    case 3: rp_linT(a.lin1W, a.lin1WT, 256, 256, idx); break;
    case 4: rp_pqT (a.pre2W, a.pre2b, a.WpqT2, a.bpq2, 256, 32, idx); break;
    case 5: rp_xT  (a.post2W, a.post2b, a.WxT2, a.bpost2, 256, 32, idx); break;
    case 6: rp_agg3(a.post2W, a.Wagg32, 256, 32, idx); break;
    case 7: rp_linT(a.lin2W, a.lin2WT, 128, 128, idx); break;
    case 8:
      for (int i = idx; i < a.nx4; i += a.gstride){
        float4 v = *(const float4*)(a.x + (size_t)i*4);
        ushort4 o = make_ushort4(f2bu(v.x), f2bu(v.y), f2bu(v.z), f2bu(v.w));
        *(ushort4*)(a.x_bf + (size_t)i*4) = o;
      }
      break;
    case 9:
      for (int e = idx; e < a.E; e += a.gstride)
        atomicAdd(&a.deg[a.tgt[e]], 1);
      break;
  }
}

// ---------------- MFMA GEMM: C[N, *] = A[N,K](bf16) @ Bt[NC,K]^T (bf16) ----------------
// 64x64 tile, 4 waves, double-buffered global_load_lds. XCD-chunk swizzled so the
// j-blocks sharing an A row-panel colocate on one XCD's L2 (T1).
// STATS: per-column {sum, sumsq} atomically accumulated into stats[2*ldc].
template<typename TO, bool STATS>
__global__ __launch_bounds__(256) void k_mgemm(
    const bf16* __restrict__ A, int lda,
    const bf16* __restrict__ Bt,
    const float* __restrict__ bias,
    TO* __restrict__ Cout, int ldc,
    int N, int K, int NC, float* __restrict__ stats)
{
  __shared__ __align__(16) bf16 As[2][64*32];
  __shared__ __align__(16) bf16 Bs[2][64*32];
  __shared__ float sstat[4][2][16][2];
  int bx = blockIdx.x, by = blockIdx.y;
  xcd_remap(gridDim.x, gridDim.x*gridDim.y, bx, by);
  int n0 = by*64;
  int j0 = bx*64;
  int tid = threadIdx.x;
  int srow = tid>>2, skoff = (tid&3)*8;
  int wave = tid>>6, lane = tid&63;
  int wy = (wave>>1)*32, wx = (wave&1)*32;
  int l15 = lane&15, q = lane>>4;
  f32x4 acc[2][2] = {};
  const bf16* Ag = A  + (size_t)(n0 + srow)*lda + skoff;
  const bf16* Bg = Bt + (size_t)(j0 + srow)*K   + skoff;
  int nt = K >> 5;
  // prologue: stage K-tile 0 into buffer 0
  gl_lds16(Ag, &As[0][tid*8]);
  gl_lds16(Bg, &Bs[0][tid*8]);
  __syncthreads();
  for (int t = 0; t < nt; t++){
    int cur = t & 1;
    if (t + 1 < nt){
      gl_lds16(Ag + (t+1)*32, &As[cur^1][tid*8]);
      gl_lds16(Bg + (t+1)*32, &Bs[cur^1][tid*8]);
    }
    short8 af[2], bfr[2];
    #pragma unroll
    for (int i = 0; i < 2; i++){
      af[i]  = *(const short8*)&As[cur][(wy + i*16 + l15)*32 + q*8];
      bfr[i] = *(const short8*)&Bs[cur][(wx + i*16 + l15)*32 + q*8];
    }
    #pragma unroll
    for (int mi = 0; mi < 2; mi++)
      #pragma unroll
      for (int ni = 0; ni < 2; ni++)
        acc[mi][ni] = __builtin_amdgcn_mfma_f32_16x16x32_bf16(af[mi], bfr[ni], acc[mi][ni], 0, 0, 0);
    __syncthreads();
  }
  float cs[2] = {0.f, 0.f}, cq[2] = {0.f, 0.f};
  #pragma unroll
  for (int mi = 0; mi < 2; mi++){
    #pragma unroll
    for (int ni = 0; ni < 2; ni++){
      #pragma unroll
      for (int r = 0; r < 4; r++){
        int n  = n0 + wy + mi*16 + q*4 + r;
        int jj = j0 + wx + ni*16 + l15;
        if (n < N && jj < NC){
          float v = acc[mi][ni][r] + bias[jj];
          stv(&Cout[(size_t)n*ldc + jj], v);
          if constexpr (STATS){ cs[ni] += v; cq[ni] = fmaf(v, v, cq[ni]); }
        }
      }
    }
  }
  if constexpr (STATS){
    #pragma unroll
    for (int ni = 0; ni < 2; ni++){
      float s = cs[ni], qq = cq[ni];
      s  += __shfl_xor(s, 16);  s  += __shfl_xor(s, 32);
      qq += __shfl_xor(qq, 16); qq += __shfl_xor(qq, 32);
      if (q == 0){ sstat[wave][ni][l15][0] = s; sstat[wave][ni][l15][1] = qq; }
    }
    __syncthreads();
    if (tid < 64){
      int j = tid;
      int wa = (j < 32) ? 0 : 1, wb = wa + 2;
      int ni = (j & 31) >> 4, li = j & 15;
      float s  = sstat[wa][ni][li][0] + sstat[wb][ni][li][0];
      float qq = sstat[wa][ni][li][1] + sstat[wb][ni][li][1];
      atomicAdd(&stats[j0 + j], s);
      atomicAdd(&stats[ldc + j0 + j], qq);
    }
  }
}

// ---------------- post-agg GEMM (phase-2 only): Cin (x@Wx+bias, bf16) read from PQX ----------------
// NO LDS, NO BARRIERS: A (agg) has zero cross-block reuse (each tower-z reads a
// disjoint column slice) and only 2-way intra-block reuse; B (Wagg3, <=393KB) is
// L2-resident. Each lane loads its MFMA fragments directly from global (16B at
// row=..+l15, kchunk=q*8 -> a wave touches 16 rows x 64B). Pure load->MFMA dataflow;
// the compiler software-pipelines across the fully-unrolled k-loop; latency is hidden
// by high occupancy (no LDS cap, ~100 VGPR).
template<int COLS>
__global__ __launch_bounds__(256) void k_postagg(
    const bf16* __restrict__ agg,      // [N, 16*COLS]
    const bf16* __restrict__ Wagg3,    // [T][3*COLS][K4F]
    const bf16* __restrict__ PQX, int ldq, int cinOff,
    const float* __restrict__ scal,
    bf16* __restrict__ Cout, int ldc, int N)
{
  constexpr int K4F = 4*COLS;
  constexpr int ROWS3 = 3*COLS;
  constexpr int NI = COLS/32;          // 2 (COLS=64) or 1 (COLS=32)
  constexpr int LDA_AGG = 16*COLS;
  constexpr int NT = K4F/32;
  int z = blockIdx.z;
  int n0 = blockIdx.y*64;
  int tid = threadIdx.x;
  int wave = tid>>6, lane = tid&63;
  int wy = (wave>>1)*32;
  int wx = (wave&1)*(COLS/2);
  int l15 = lane&15, q = lane>>4;
  f32x4 acc[2][NI][3] = {};
  // per-lane fragment bases (OOB A-rows in the last block read in-workspace garbage
  // that only feeds discarded output rows; B rows are always in-range)
  const bf16* Ab = agg + (size_t)z*K4F + (size_t)(n0 + wy + l15)*LDA_AGG + q*8;
  const bf16* Bb = Wagg3 + (size_t)z*ROWS3*K4F + (size_t)(wx + l15)*K4F + q*8;
  #pragma unroll
  for (int t = 0; t < NT; t++){
    short8 af[2];
    #pragma unroll
    for (int i = 0; i < 2; i++)
      af[i] = *(const short8*)(Ab + (size_t)i*16*LDA_AGG + t*32);
    #pragma unroll
    for (int s = 0; s < 3; s++){
      #pragma unroll
      for (int ni = 0; ni < NI; ni++){
        short8 bfr = *(const short8*)(Bb + (size_t)(s*COLS + ni*16)*K4F + t*32);
        #pragma unroll
        for (int mi = 0; mi < 2; mi++)
          acc[mi][ni][s] = __builtin_amdgcn_mfma_f32_16x16x32_bf16(af[mi], bfr, acc[mi][ni][s], 0, 0, 0);
      }
    }
  }
  #pragma unroll
  for (int mi = 0; mi < 2; mi++){
    #pragma unroll
    for (int ni = 0; ni < NI; ni++){
      int jj = wx + ni*16 + l15;
      int jg = z*COLS + jj;
      #pragma unroll
      for (int r = 0; r < 4; r++){
        int n = n0 + wy + mi*16 + q*4 + r;
        if (n < N){
          float s1 = scal[2*n], s2 = scal[2*n+1];
          float cin = bf2f(PQX[(size_t)n*ldq + cinOff + jg]);
          float v = cin + acc[mi][ni][0][r] + s1*acc[mi][ni][1][r] + s2*acc[mi][ni][2][r];
          Cout[(size_t)n*ldc + jg] = __float2bfloat16(v);
        }
      }
    }
  }
}

// ---------------- per-node PNA aggregation -> agg [N, T*4F] bf16 + scal ----------------
// One wave per node; 64 lanes each own VEC=NC/64 columns. n/offs readfirstlane'd so
// index loads scalarize to the SMEM pipe. Edge loop split into UNCLAMPED full groups
// of 8 (no min(), no masks in the hot path) + ONE masked tail group; next group's
// indices always prefetched so SMEM latency hides under the current group's gathers.
template<int NC, int F, int LDA>
__global__ __launch_bounds__(256) void k_agg(const bf16* __restrict__ PQ,
    const int* __restrict__ ssrc, const int* __restrict__ offs,
    const float* __restrict__ avgp,
    bf16* __restrict__ agg, float* __restrict__ scal, int N)
{
  constexpr int VEC = NC/64;   // 4 (L1) or 2 (L2)
  int lane = threadIdx.x & 63;
  int n = __builtin_amdgcn_readfirstlane((int)(blockIdx.x*4 + (threadIdx.x>>6)));
  if (n >= N) return;
  int c0 = lane*VEC;
  float p[VEC];
  ldbf<VEC>(PQ + (size_t)n*LDA + c0, p);
  int s0 = __builtin_amdgcn_readfirstlane(offs[n]);
  int s1 = __builtin_amdgcn_readfirstlane(offs[n+1]);
  int deg = s1 - s0;
  float sum[VEC], sq[VEC], mn[VEC], mx[VEC];
  #pragma unroll
  for (int v=0;v<VEC;v++){ sum[v]=0.f; sq[v]=0.f; mn[v]=FLT_MAX; mx[v]=-FLT_MAX; }
  const bf16* Q = PQ + NC + c0;
  if (deg > 0){
    int last = s1 - 1;
    int nfull = deg >> 3;
    int tail  = deg & 7;
    int se[8], sn[8];
    if (nfull > 0){
      #pragma unroll
      for (int u=0;u<8;u++) se[u] = ssrc[s0+u];
    } else {
      #pragma unroll
      for (int u=0;u<8;u++) se[u] = ssrc[min(s0+u, last)];
    }
    for (int g = 0; g < nfull; g++){
      bool moref = (g + 1 < nfull);
      bool tailn = (g + 1 == nfull) && (tail != 0);
      int base = s0 + (g+1)*8;
      if (moref){
        #pragma unroll
        for (int u=0;u<8;u++) sn[u] = ssrc[base+u];
      } else if (tailn){
        #pragma unroll
        for (int u=0;u<8;u++) sn[u] = ssrc[min(base+u, last)];
      }
      float qv[8][VEC];
      #pragma unroll
      for (int u=0;u<8;u++) ldbf<VEC>(Q + (size_t)se[u]*LDA, qv[u]);
      #pragma unroll
      for (int u=0;u<8;u++){
        #pragma unroll
        for (int v=0;v<VEC;v++){
          float qq = qv[u][v];
          sum[v] += qq; sq[v] = fmaf(qq,qq,sq[v]);
          mn[v] = fminf(mn[v],qq); mx[v] = fmaxf(mx[v],qq);
        }
      }
      if (moref || tailn){
        #pragma unroll
        for (int u=0;u<8;u++) se[u] = sn[u];
      }
    }
    if (tail){
      // se holds clamped indices (duplicates of last edge beyond tail):
      // min/max idempotent under duplicates; sum/sq masked.
      float qv[8][VEC];
      #pragma unroll
      for (int u=0;u<8;u++) ldbf<VEC>(Q + (size_t)se[u]*LDA, qv[u]);
      #pragma unroll
      for (int u=0;u<8;u++){
        bool valid = u < tail;
        #pragma unroll
        for (int v=0;v<VEC;v++){
          float qq = qv[u][v];
          float tq = valid ? qq : 0.f;
          sum[v] += tq; sq[v] = fmaf(tq,qq,sq[v]);
          mn[v] = fminf(mn[v],qq); mx[v] = fmaxf(mx[v],qq);
        }
      }
    }
  }
  float degf = (float)deg;
  float degc = fmaxf(degf, 1.f);
  float rdeg = 1.f/degc;
  unsigned short um[VEC], un[VEC], ux[VEC], us[VEC];
  #pragma unroll
  for (int v=0;v<VEC;v++){
    float pv = p[v];
    float sum_m = fmaf(degf, pv, sum[v]);
    float sq_m  = sq[v] + 2.f*pv*sum[v] + degf*pv*pv;
    float mean = sum_m*rdeg;
    float var = fmaxf(fmaf(sq_m, rdeg, -mean*mean), 0.f);
    float sd = sqrtf(var + 1e-5f);
    float mnv = deg>0 ? pv + mn[v] : 0.f;
    float mxv = deg>0 ? pv + mx[v] : 0.f;
    um[v]=f2bu(mean); un[v]=f2bu(mnv); ux[v]=f2bu(mxv); us[v]=f2bu(sd);
  }
  int t = c0 / F, f0 = c0 % F;
  bf16* base = agg + (size_t)n*4*NC + (size_t)t*4*F + f0;
  if constexpr (VEC==4){
    *(ushort4*)(base)       = make_ushort4(um[0],um[1],um[2],um[3]);
    *(ushort4*)(base + F)   = make_ushort4(un[0],un[1],un[2],un[3]);
    *(ushort4*)(base + 2*F) = make_ushort4(ux[0],ux[1],ux[2],ux[3]);
    *(ushort4*)(base + 3*F) = make_ushort4(us[0],us[1],us[2],us[3]);
  } else {
    *(ushort2*)(base)       = make_ushort2(um[0],um[1]);
    *(ushort2*)(base + F)   = make_ushort2(un[0],un[1]);
    *(ushort2*)(base + 2*F) = make_ushort2(ux[0],ux[1]);
    *(ushort2*)(base + 3*F) = make_ushort2(us[0],us[1]);
  }
  if (lane == 0){
    float dlog = logf(degc + 1.f);
    float avg = *avgp;
    scal[2*n]   = dlog/avg;
    scal[2*n+1] = avg/dlog;
  }
}

// ---------------- batch norm apply (stats accumulated by k_mgemm STATS) ----------------
template<typename TO, int C>
__global__ void k_bn_apply(const bf16* __restrict__ h, const float* __restrict__ stats,
     const float* __restrict__ g, const float* __restrict__ b,
     TO* __restrict__ out, int N){
  int idx = blockIdx.x*blockDim.x + threadIdx.x;   // quad index
  if (idx >= N*(C/4)) return;
  int c = (idx % (C/4))*4;
  float fn = (float)N;
  float v[4];
  ldbf<4>(h + (size_t)idx*4, v);
  float r[4];
  #pragma unroll
  for (int k = 0; k < 4; k++){
    float m = stats[c+k]/fn;
    float var = fmaxf(stats[C+c+k]/fn - m*m, 0.f);
    float inv = rsqrtf(var + 1e-5f);
    float vv = nanfix(v[k]);
    r[k] = fmaxf(g[c+k]*(vv - m)*inv + b[c+k], 0.f);
  }
  if constexpr (sizeof(TO) == 4){
    float4 o = {r[0], r[1], r[2], r[3]};
    *(float4*)((float*)out + (size_t)idx*4) = o;
  } else {
    ushort4 o = make_ushort4(f2bu(r[0]), f2bu(r[1]), f2bu(r[2]), f2bu(r[3]));
    *(ushort4*)((bf16*)out + (size_t)idx*4) = o;
  }
}

static inline int cdiv(int a, int b){ return (a + b - 1)/b; }

extern "C" void kernel_launch(void* const* d_in, const int* in_sizes, int n_in,
                              void* d_out, int out_size, void* d_ws, size_t ws_size,
                              hipStream_t stream){
  const int IN = 128, HID = 256, T = 4, F1 = 64, F2 = 32;
  const int N = in_sizes[0]/IN;
  const int E = in_sizes[1]/2;
  const int NC1 = T*F1;        // 256
  const int NC2 = T*F2;        // 128
  const int LDQ1 = 2*NC1 + NC1;   // 768: [P|Q|postX]
  const int LDQ2 = 2*NC2 + NC2;   // 384

  const float* x      = (const float*)d_in[0];
  const int*   ei     = (const int*)  d_in[1];
  const int*   srcE   = ei;
  const int*   tgtE   = ei + E;
  const float* avgp   = (const float*)d_in[2];
  const float* pre1W  = (const float*)d_in[3];
  const float* pre1b  = (const float*)d_in[4];
  const float* post1W = (const float*)d_in[5];
  const float* post1b = (const float*)d_in[6];
  const float* lin1W  = (const float*)d_in[7];
  const float* lin1b  = (const float*)d_in[8];
  const float* bn1g   = (const float*)d_in[9];
  const float* bn1b   = (const float*)d_in[10];
  const float* pre2W  = (const float*)d_in[11];
  const float* pre2b  = (const float*)d_in[12];
  const float* post2W = (const float*)d_in[13];
  const float* post2b = (const float*)d_in[14];
  const float* lin2W  = (const float*)d_in[15];
  const float* lin2b  = (const float*)d_in[16];
  const float* bn2g   = (const float*)d_in[17];
  const float* bn2b   = (const float*)d_in[18];

  // ---- workspace carve ----
  char* w = (char*)d_ws;
  auto alloc = [&](size_t bytes)->void*{
    void* p = (void*)w; w += (bytes + 255) & ~(size_t)255; return p;
  };
  // combined B^T for pre-GEMM: [WpqT (2*NC rows) | WxT (NC rows)], contiguous
  bf16* BT1    = (bf16*)alloc((size_t)LDQ1*IN*2);
  bf16* WpqT1  = BT1;              bf16* WxT1 = BT1 + (size_t)2*NC1*IN;
  float* bias1 = (float*)alloc((size_t)LDQ1*4);
  float* bpq1  = bias1;            float* bpost1 = bias1 + 2*NC1;
  bf16* Wagg31 = (bf16*)alloc((size_t)T*3*F1*4*F1*2);
  bf16* lin1WT = (bf16*)alloc((size_t)HID*NC1*2);
  bf16* BT2    = (bf16*)alloc((size_t)LDQ2*HID*2);
  bf16* WpqT2  = BT2;              bf16* WxT2 = BT2 + (size_t)2*NC2*HID;
  float* bias2 = (float*)alloc((size_t)LDQ2*4);
  float* bpq2  = bias2;            float* bpost2 = bias2 + 2*NC2;
  bf16* Wagg32 = (bf16*)alloc((size_t)T*3*F2*4*F2*2);
  bf16* lin2WT = (bf16*)alloc((size_t)128*NC2*2);
  // zero region: deg_i | cnt | stats (one memset)
  int* deg_i   = (int*)alloc((size_t)N*4);
  int* cnt     = (int*)alloc((size_t)N*4);
  float* stats = (float*)alloc(1024*4);
  size_t zbytes = (size_t)((char*)stats - (char*)deg_i) + 1024*4;
  int* offs    = (int*)alloc((size_t)(N+1)*4);
  int* bsum    = (int*)alloc((size_t)cdiv(N,256)*4);
  int* ssrc    = (int*)alloc((size_t)E*4);
  bf16* x_bf   = (bf16*)alloc((size_t)N*IN*2);
  bf16* PQX    = (bf16*)alloc((size_t)N*LDQ1*2);   // L2 reuses prefix [N, LDQ2]
  bf16* aggb   = (bf16*)alloc((size_t)N*4*NC1*2);  // L2 reuses prefix [N, 4*NC2]
  float* scal  = (float*)alloc((size_t)N*2*4);
  bf16* postbb = (bf16*)alloc((size_t)N*256*2);
  bf16* hpre   = (bf16*)alloc((size_t)N*256*2);
  bf16* h1b    = (bf16*)alloc((size_t)N*256*2);
  int NB = cdiv(N,64);

  hipMemsetAsync(deg_i, 0, zbytes, stream);

  // ---- setup: all weight repacks + x conversion + degree count (one dispatch) ----
  int sgx = cdiv(T*3*F1*4*F1, 256);   // 768 blocks covers the largest segment
  SetupArgs sa = { pre1W, pre1b, post1W, post1b, lin1W,
                   pre2W, pre2b, post2W, post2b, lin2W,
                   x, tgtE,
                   WpqT1, WxT1, Wagg31, lin1WT,
                   WpqT2, WxT2, Wagg32, lin2WT,
                   x_bf, deg_i,
                   bpq1, bpost1, bpq2, bpost2,
                   N*IN/4, E, sgx*256 };
  k_setup<<<dim3(sgx, 10),256,0,stream>>>(sa);

  // ---- counting sort of edges by target (parallel scan) ----
  int NBs = cdiv(N,256);
  k_scan1<<<NBs,256,0,stream>>>(deg_i, bsum, N);
  k_scan2<<<1,1024,0,stream>>>(bsum, NBs);
  k_scan3<<<NBs,256,0,stream>>>(deg_i, bsum, offs, N);
  k_scatter<<<cdiv(E,256),256,0,stream>>>(srcE, tgtE, offs, cnt, ssrc, E);

  // ================= Layer 1 =================
  k_mgemm<bf16,false><<<dim3(LDQ1/64,NB),256,0,stream>>>(x_bf, IN, BT1, bias1, PQX, LDQ1, N, IN, LDQ1, nullptr);
  k_agg<256,64,768><<<cdiv(N,4),256,0,stream>>>(PQX, ssrc, offs, avgp, aggb, scal, N);
  k_postagg<64><<<dim3(1,NB,T),256,0,stream>>>(aggb, Wagg31, PQX, LDQ1, 2*NC1, scal,
                                               postbb, NC1, N);
  k_mgemm<bf16,true><<<dim3(4,NB),256,0,stream>>>(postbb, NC1, lin1WT, lin1b, hpre, HID, N, NC1, HID, stats);
  k_bn_apply<bf16,256><<<cdiv(N*64,256),256,0,stream>>>(hpre, stats, bn1g, bn1b, h1b, N);

  // ================= Layer 2 =================
  k_mgemm<bf16,false><<<dim3(LDQ2/64,NB),256,0,stream>>>(h1b, HID, BT2, bias2, PQX, LDQ2, N, HID, LDQ2, nullptr);
  k_agg<128,32,384><<<cdiv(N,4),256,0,stream>>>(PQX, ssrc, offs, avgp, aggb, scal, N);
  k_postagg<32><<<dim3(1,NB,T),256,0,stream>>>(aggb, Wagg32, PQX, LDQ2, 2*NC2, scal,
                                               postbb, NC2, N);
  k_mgemm<bf16,true><<<dim3(2,NB),256,0,stream>>>(postbb, NC2, lin2WT, lin2b, hpre, 128, N, NC2, 128, stats + 512);
  k_bn_apply<float,128><<<cdiv(N*32,256),256,0,stream>>>(hpre, stats + 512, bn2g, bn2b, (float*)d_out, N);
}

// Round 6
// 341.003 us; speedup vs baseline: 1.1468x; 1.1468x over previous
//
#include <hip/hip_runtime.h>
#include <hip/hip_bf16.h>
#include <float.h>
#include <math.h>

typedef __hip_bfloat16 bf16;
typedef __attribute__((ext_vector_type(8))) short short8;
typedef __attribute__((ext_vector_type(4))) float f32x4;

__device__ __forceinline__ float bf2f(bf16 v){ return __bfloat162float(v); }
__device__ __forceinline__ void stv(float* p, float v){ *p = v; }
__device__ __forceinline__ void stv(bf16* p, float v){ *p = __float2bfloat16(v); }
__device__ __forceinline__ float nanfix(float v){
  if (v != v) return 0.f;
  return fminf(fmaxf(v, -FLT_MAX), FLT_MAX);
}
__device__ __forceinline__ unsigned short f2bu(float f){
  unsigned u = __float_as_uint(f);
  unsigned r = u + 0x7FFFu + ((u>>16)&1u);
  return (unsigned short)(r>>16);
}
template<int VEC>
__device__ __forceinline__ void ldbf(const bf16* p, float (&o)[VEC]){
  if constexpr (VEC==4){
    ushort4 r = *(const ushort4*)p;
    o[0]=__uint_as_float((unsigned)r.x<<16); o[1]=__uint_as_float((unsigned)r.y<<16);
    o[2]=__uint_as_float((unsigned)r.z<<16); o[3]=__uint_as_float((unsigned)r.w<<16);
  } else {
    ushort2 r = *(const ushort2*)p;
    o[0]=__uint_as_float((unsigned)r.x<<16); o[1]=__uint_as_float((unsigned)r.y<<16);
  }
}

// async global->LDS, 16B per lane. LDS dest must be wave-uniform base + lane*16.
__device__ __forceinline__ void gl_lds16(const bf16* g, bf16* l){
  __builtin_amdgcn_global_load_lds(
      (const __attribute__((address_space(1))) void*)g,
      (__attribute__((address_space(3))) void*)l, 16, 0, 0);
}

// counted vmcnt wait (T4): wait until at most N vector-memory ops outstanding.
template<int N> __device__ __forceinline__ void waitvm(){
  if constexpr (N==0)      asm volatile("s_waitcnt vmcnt(0)" ::: "memory");
  else if constexpr (N==2) asm volatile("s_waitcnt vmcnt(2)" ::: "memory");
  else if constexpr (N==3) asm volatile("s_waitcnt vmcnt(3)" ::: "memory");
  else if constexpr (N==4) asm volatile("s_waitcnt vmcnt(4)" ::: "memory");
}

// bijective XCD-chunk remap (m204)
__device__ __forceinline__ void xcd_remap(int gx, int total, int &bx, int &by){
  int orig = by*gx + bx;
  int q8 = total >> 3, r8 = total & 7;
  int xcd = orig & 7, rest = orig >> 3;
  int nid = (xcd < r8) ? (xcd*(q8+1) + rest)
                       : (r8*(q8+1) + (xcd-r8)*q8 + rest);
  bx = nid % gx; by = nid / gx;
}

// ---------------- parallel scan + scatter (deg lives in k_setup) ----------------
__global__ void k_scan1(const int* __restrict__ deg, int* __restrict__ bsum, int N){
  __shared__ int sm[256];
  int i = blockIdx.x*256 + threadIdx.x;
  sm[threadIdx.x] = (i < N) ? deg[i] : 0;
  __syncthreads();
  for (int off = 128; off > 0; off >>= 1){
    if (threadIdx.x < off) sm[threadIdx.x] += sm[threadIdx.x + off];
    __syncthreads();
  }
  if (threadIdx.x == 0) bsum[blockIdx.x] = sm[0];
}

__global__ void k_scan2(int* __restrict__ bsum, int NB){
  __shared__ int sm[1024];
  int tid = threadIdx.x;
  sm[tid] = (tid < NB) ? bsum[tid] : 0;
  __syncthreads();
  for (int off = 1; off < 1024; off <<= 1){
    int t = (tid >= off) ? sm[tid-off] : 0;
    __syncthreads();
    sm[tid] += t;
    __syncthreads();
  }
  if (tid < NB) bsum[tid] = (tid == 0) ? 0 : sm[tid-1];   // exclusive block offsets
}

__global__ void k_scan3(const int* __restrict__ deg, const int* __restrict__ bsum,
                        int* __restrict__ offs, int N){
  __shared__ int sm[256];
  int tid = threadIdx.x;
  int i = blockIdx.x*256 + tid;
  int v = (i < N) ? deg[i] : 0;
  sm[tid] = v; __syncthreads();
  for (int off = 1; off < 256; off <<= 1){
    int t = (tid >= off) ? sm[tid-off] : 0;
    __syncthreads();
    sm[tid] += t;
    __syncthreads();
  }
  if (i < N) offs[i+1] = bsum[blockIdx.x] + sm[tid];
  if (i == 0) offs[0] = 0;
}

__global__ void k_scatter(const int* __restrict__ src, const int* __restrict__ tgt,
                          const int* __restrict__ offs, int* __restrict__ cnt,
                          int* __restrict__ ssrc, int E){
  int e = blockIdx.x*blockDim.x + threadIdx.x;
  if (e < E){
    int t = tgt[e];
    int pos = offs[t] + atomicAdd(&cnt[t], 1);
    ssrc[pos] = src[e];
  }
}

// ---------------- fused setup: weight repacks + x conversion + degree count ----------------
__device__ __forceinline__ void rp_pqT(const float* preW, const float* preB,
                                       bf16* WpqT, float* bpq, int K, int F, int idx){
  int NC = 4*F;
  int total = 2*NC*K;
  if (idx < total){
    int j = idx/K, c = idx%K;
    int half = j/NC, jj = j%NC, t = jj/F, f = jj%F;
    WpqT[idx] = __float2bfloat16(preW[(t*2*K + half*K + c)*F + f]);
  }
  if (idx < 2*NC) bpq[idx] = (idx < NC) ? preB[idx] : 0.f;
}
__device__ __forceinline__ void rp_xT(const float* postW, const float* postB,
                                      bf16* WxT, float* bpost, int KX, int F, int idx){
  int NC = 4*F; int KP = KX + 12*F;
  if (idx < NC*KX){
    int j = idx/KX, c = idx%KX, t = j/F, f = j%F;
    WxT[idx] = __float2bfloat16(postW[(t*KP + c)*F + f]);
  }
  if (idx < NC) bpost[idx] = postB[idx];
}
__device__ __forceinline__ void rp_agg3(const float* postW, bf16* Wagg3,
                                        int KX, int F, int idx){
  int K4F = 4*F; int KP = KX + 12*F;
  int total = 4*3*F*K4F;
  if (idx < total){
    int k = idx % K4F; int r = idx / K4F;
    int zr = r % (3*F); int t = r / (3*F);
    int s = zr / F, f = zr % F;
    Wagg3[idx] = __float2bfloat16(postW[((size_t)(t*KP + KX + s*K4F + k))*F + f]);
  }
}
__device__ __forceinline__ void rp_linT(const float* linW, bf16* WlinT,
                                        int K, int NC, int idx){
  if (idx < NC*K){
    int j = idx/K, c = idx%K;
    WlinT[idx] = __float2bfloat16(linW[c*NC + j]);
  }
}

struct SetupArgs {
  const float *pre1W, *pre1b, *post1W, *post1b, *lin1W;
  const float *pre2W, *pre2b, *post2W, *post2b, *lin2W;
  const float *x;
  const int *tgt;
  bf16 *WpqT1, *WxT1, *Wagg31, *lin1WT;
  bf16 *WpqT2, *WxT2, *Wagg32, *lin2WT;
  bf16 *x_bf;
  int *deg;
  float *bpq1, *bpost1, *bpq2, *bpost2;
  int nx4;       // N*IN/4
  int E;
  int gstride;   // gridDim.x*256
};

__global__ void k_setup(SetupArgs a){
  int idx = blockIdx.x*256 + threadIdx.x;
  switch (blockIdx.y){
    case 0: rp_pqT (a.pre1W, a.pre1b, a.WpqT1, a.bpq1, 128, 64, idx); break;
    case 1: rp_xT  (a.post1W, a.post1b, a.WxT1, a.bpost1, 128, 64, idx); break;
    case 2: rp_agg3(a.post1W, a.Wagg31, 128, 64, idx); break;
    case 3: rp_linT(a.lin1W, a.lin1WT, 256, 256, idx); break;
    case 4: rp_pqT (a.pre2W, a.pre2b, a.WpqT2, a.bpq2, 256, 32, idx); break;
    case 5: rp_xT  (a.post2W, a.post2b, a.WxT2, a.bpost2, 256, 32, idx); break;
    case 6: rp_agg3(a.post2W, a.Wagg32, 256, 32, idx); break;
    case 7: rp_linT(a.lin2W, a.lin2WT, 128, 128, idx); break;
    case 8:
      for (int i = idx; i < a.nx4; i += a.gstride){
        float4 v = *(const float4*)(a.x + (size_t)i*4);
        ushort4 o = make_ushort4(f2bu(v.x), f2bu(v.y), f2bu(v.z), f2bu(v.w));
        *(ushort4*)(a.x_bf + (size_t)i*4) = o;
      }
      break;
    case 9:
      for (int e = idx; e < a.E; e += a.gstride)
        atomicAdd(&a.deg[a.tgt[e]], 1);
      break;
  }
}

// ---------------- MFMA GEMM: C[N, *] = A[N,K](bf16) @ Bt[NC,K]^T (bf16) ----------------
// 64x64 tile, 4 waves, double-buffered global_load_lds with COUNTED vmcnt (T4):
// per K-step: issue stage(t+1) -> vmcnt(2) [waits only stage(t); stage(t+1) stays in
// flight across both barriers] -> raw s_barrier -> ds_read+MFMA -> raw s_barrier.
template<typename TO, bool STATS>
__global__ __launch_bounds__(256) void k_mgemm(
    const bf16* __restrict__ A, int lda,
    const bf16* __restrict__ Bt,
    const float* __restrict__ bias,
    TO* __restrict__ Cout, int ldc,
    int N, int K, int NC, float* __restrict__ stats)
{
  __shared__ __align__(16) bf16 As[2][64*32];
  __shared__ __align__(16) bf16 Bs[2][64*32];
  __shared__ float sstat[4][2][16][2];
  int bx = blockIdx.x, by = blockIdx.y;
  xcd_remap(gridDim.x, gridDim.x*gridDim.y, bx, by);
  int n0 = by*64;
  int j0 = bx*64;
  int tid = threadIdx.x;
  int srow = tid>>2, skoff = (tid&3)*8;
  int wave = tid>>6, lane = tid&63;
  int wy = (wave>>1)*32, wx = (wave&1)*32;
  int l15 = lane&15, q = lane>>4;
  f32x4 acc[2][2] = {};
  const bf16* Ag = A  + (size_t)(n0 + srow)*lda + skoff;
  const bf16* Bg = Bt + (size_t)(j0 + srow)*K   + skoff;
  int nt = K >> 5;
  // prologue: stage K-tile 0 into buffer 0 (no wait here; first iter waits)
  gl_lds16(Ag, &As[0][tid*8]);
  gl_lds16(Bg, &Bs[0][tid*8]);
  for (int t = 0; t < nt; t++){
    int cur = t & 1;
    if (t + 1 < nt){
      gl_lds16(Ag + (t+1)*32, &As[cur^1][tid*8]);
      gl_lds16(Bg + (t+1)*32, &Bs[cur^1][tid*8]);
      waitvm<2>();            // stage(t) landed; stage(t+1) still in flight
    } else {
      waitvm<0>();            // last tile: drain
    }
    __builtin_amdgcn_s_barrier();   // B1: all waves' stage(t) visible
    short8 af[2], bfr[2];
    #pragma unroll
    for (int i = 0; i < 2; i++){
      af[i]  = *(const short8*)&As[cur][(wy + i*16 + l15)*32 + q*8];
      bfr[i] = *(const short8*)&Bs[cur][(wx + i*16 + l15)*32 + q*8];
    }
    #pragma unroll
    for (int mi = 0; mi < 2; mi++)
      #pragma unroll
      for (int ni = 0; ni < 2; ni++)
        acc[mi][ni] = __builtin_amdgcn_mfma_f32_16x16x32_bf16(af[mi], bfr[ni], acc[mi][ni], 0, 0, 0);
    __builtin_amdgcn_s_barrier();   // B2: reads done before next iter overwrites buf[cur]
  }
  float cs[2] = {0.f, 0.f}, cq[2] = {0.f, 0.f};
  #pragma unroll
  for (int mi = 0; mi < 2; mi++){
    #pragma unroll
    for (int ni = 0; ni < 2; ni++){
      #pragma unroll
      for (int r = 0; r < 4; r++){
        int n  = n0 + wy + mi*16 + q*4 + r;
        int jj = j0 + wx + ni*16 + l15;
        if (n < N && jj < NC){
          float v = acc[mi][ni][r] + bias[jj];
          stv(&Cout[(size_t)n*ldc + jj], v);
          if constexpr (STATS){ cs[ni] += v; cq[ni] = fmaf(v, v, cq[ni]); }
        }
      }
    }
  }
  if constexpr (STATS){
    #pragma unroll
    for (int ni = 0; ni < 2; ni++){
      float s = cs[ni], qq = cq[ni];
      s  += __shfl_xor(s, 16);  s  += __shfl_xor(s, 32);
      qq += __shfl_xor(qq, 16); qq += __shfl_xor(qq, 32);
      if (q == 0){ sstat[wave][ni][l15][0] = s; sstat[wave][ni][l15][1] = qq; }
    }
    __syncthreads();
    if (tid < 64){
      int j = tid;
      int wa = (j < 32) ? 0 : 1, wb = wa + 2;
      int ni = (j & 31) >> 4, li = j & 15;
      float s  = sstat[wa][ni][li][0] + sstat[wb][ni][li][0];
      float qq = sstat[wa][ni][li][1] + sstat[wb][ni][li][1];
      atomicAdd(&stats[j0 + j], s);
      atomicAdd(&stats[ldc + j0 + j], qq);
    }
  }
}

// ---------------- post-agg GEMM (phase-2 only): Cin (x@Wx+bias, bf16) read from PQX ----------------
// R1-proven 64-row / 32-wide geometry + counted-vmcnt pipeline (T4).
// B panel padded to a multiple of 64 rows so every wave issues a uniform load count
// (pad rows read in-workspace garbage never consumed from LDS).
template<int COLS>
__global__ __launch_bounds__(256) void k_postagg(
    const bf16* __restrict__ agg,      // [N, 16*COLS]
    const bf16* __restrict__ Wagg3,    // [T][3*COLS][K4F]
    const bf16* __restrict__ PQX, int ldq, int cinOff,
    const float* __restrict__ scal,
    bf16* __restrict__ Cout, int ldc, int N)
{
  constexpr int K4F = 4*COLS;
  constexpr int ROWS3 = 3*COLS;
  constexpr int ROWS3P = (ROWS3 + 63) & ~63;   // 192 (COLS=64) / 128 (COLS=32)
  constexpr int BROW3 = ROWS3P/64;             // 3 / 2
  constexpr int NLD = 1 + BROW3;               // loads per stage per wave: 4 / 3
  constexpr int NI = COLS/32;                  // 2 (COLS=64) or 1 (COLS=32)
  constexpr int LDA_AGG = 16*COLS;
  __shared__ __align__(16) bf16 As[2][64*32];
  __shared__ __align__(16) bf16 Bs[2][ROWS3P*32];
  int z = blockIdx.z;
  int n0 = blockIdx.y*64;
  int tid = threadIdx.x;
  int srow = tid>>2, skoff = (tid&3)*8;
  int wave = tid>>6, lane = tid&63;
  int wy = (wave>>1)*32;
  int wx = (wave&1)*(COLS/2);
  int l15 = lane&15, q = lane>>4;
  f32x4 acc[2][NI][3] = {};
  const bf16* Ag = agg + (size_t)z*K4F + (size_t)(n0 + srow)*LDA_AGG + skoff;
  const bf16* Bg = Wagg3 + (size_t)z*ROWS3*K4F + (size_t)srow*K4F + skoff;
  constexpr int NT = K4F/32;
  // prologue: stage K-tile 0 (uniform NLD loads per wave)
  gl_lds16(Ag, &As[0][tid*8]);
  #pragma unroll
  for (int r = 0; r < BROW3; r++)
    gl_lds16(Bg + (size_t)r*64*K4F, &Bs[0][(srow + r*64)*32 + skoff]);
  for (int t = 0; t < NT; t++){
    int cur = t & 1;
    if (t + 1 < NT){
      gl_lds16(Ag + (t+1)*32, &As[cur^1][tid*8]);
      #pragma unroll
      for (int r = 0; r < BROW3; r++)
        gl_lds16(Bg + (size_t)r*64*K4F + (t+1)*32, &Bs[cur^1][(srow + r*64)*32 + skoff]);
      waitvm<NLD>();          // stage(t) landed; stage(t+1) stays in flight
    } else {
      waitvm<0>();
    }
    __builtin_amdgcn_s_barrier();   // B1
    short8 af[2];
    #pragma unroll
    for (int i = 0; i < 2; i++)
      af[i] = *(const short8*)&As[cur][(wy + i*16 + l15)*32 + q*8];
    #pragma unroll
    for (int s = 0; s < 3; s++){
      #pragma unroll
      for (int ni = 0; ni < NI; ni++){
        short8 bfr = *(const short8*)&Bs[cur][(s*COLS + wx + ni*16 + l15)*32 + q*8];
        #pragma unroll
        for (int mi = 0; mi < 2; mi++)
          acc[mi][ni][s] = __builtin_amdgcn_mfma_f32_16x16x32_bf16(af[mi], bfr, acc[mi][ni][s], 0, 0, 0);
      }
    }
    __builtin_amdgcn_s_barrier();   // B2
  }
  #pragma unroll
  for (int mi = 0; mi < 2; mi++){
    #pragma unroll
    for (int ni = 0; ni < NI; ni++){
      int jj = wx + ni*16 + l15;
      int jg = z*COLS + jj;
      #pragma unroll
      for (int r = 0; r < 4; r++){
        int n = n0 + wy + mi*16 + q*4 + r;
        if (n < N){
          float s1 = scal[2*n], s2 = scal[2*n+1];
          float cin = bf2f(PQX[(size_t)n*ldq + cinOff + jg]);
          float v = cin + acc[mi][ni][0][r] + s1*acc[mi][ni][1][r] + s2*acc[mi][ni][2][r];
          Cout[(size_t)n*ldc + jg] = __float2bfloat16(v);
        }
      }
    }
  }
}

// ---------------- per-node PNA aggregation -> agg [N, T*4F] bf16 + scal ----------------
template<int NC, int F, int LDA>
__global__ __launch_bounds__(256) void k_agg(const bf16* __restrict__ PQ,
    const int* __restrict__ ssrc, const int* __restrict__ offs,
    const float* __restrict__ avgp,
    bf16* __restrict__ agg, float* __restrict__ scal, int N)
{
  constexpr int VEC = NC/64;   // 4 (L1) or 2 (L2)
  int lane = threadIdx.x & 63;
  int n = __builtin_amdgcn_readfirstlane((int)(blockIdx.x*4 + (threadIdx.x>>6)));
  if (n >= N) return;
  int c0 = lane*VEC;
  float p[VEC];
  ldbf<VEC>(PQ + (size_t)n*LDA + c0, p);
  int s0 = __builtin_amdgcn_readfirstlane(offs[n]);
  int s1 = __builtin_amdgcn_readfirstlane(offs[n+1]);
  int deg = s1 - s0;
  float sum[VEC], sq[VEC], mn[VEC], mx[VEC];
  #pragma unroll
  for (int v=0;v<VEC;v++){ sum[v]=0.f; sq[v]=0.f; mn[v]=FLT_MAX; mx[v]=-FLT_MAX; }
  const bf16* Q = PQ + NC + c0;
  if (deg > 0){
    int last = s1 - 1;
    int nfull = deg >> 3;
    int tail  = deg & 7;
    int se[8], sn[8];
    if (nfull > 0){
      #pragma unroll
      for (int u=0;u<8;u++) se[u] = ssrc[s0+u];
    } else {
      #pragma unroll
      for (int u=0;u<8;u++) se[u] = ssrc[min(s0+u, last)];
    }
    for (int g = 0; g < nfull; g++){
      bool moref = (g + 1 < nfull);
      bool tailn = (g + 1 == nfull) && (tail != 0);
      int base = s0 + (g+1)*8;
      if (moref){
        #pragma unroll
        for (int u=0;u<8;u++) sn[u] = ssrc[base+u];
      } else if (tailn){
        #pragma unroll
        for (int u=0;u<8;u++) sn[u] = ssrc[min(base+u, last)];
      }
      float qv[8][VEC];
      #pragma unroll
      for (int u=0;u<8;u++) ldbf<VEC>(Q + (size_t)se[u]*LDA, qv[u]);
      #pragma unroll
      for (int u=0;u<8;u++){
        #pragma unroll
        for (int v=0;v<VEC;v++){
          float qq = qv[u][v];
          sum[v] += qq; sq[v] = fmaf(qq,qq,sq[v]);
          mn[v] = fminf(mn[v],qq); mx[v] = fmaxf(mx[v],qq);
        }
      }
      if (moref || tailn){
        #pragma unroll
        for (int u=0;u<8;u++) se[u] = sn[u];
      }
    }
    if (tail){
      float qv[8][VEC];
      #pragma unroll
      for (int u=0;u<8;u++) ldbf<VEC>(Q + (size_t)se[u]*LDA, qv[u]);
      #pragma unroll
      for (int u=0;u<8;u++){
        bool valid = u < tail;
        #pragma unroll
        for (int v=0;v<VEC;v++){
          float qq = qv[u][v];
          float tq = valid ? qq : 0.f;
          sum[v] += tq; sq[v] = fmaf(tq,qq,sq[v]);
          mn[v] = fminf(mn[v],qq); mx[v] = fmaxf(mx[v],qq);
        }
      }
    }
  }
  float degf = (float)deg;
  float degc = fmaxf(degf, 1.f);
  float rdeg = 1.f/degc;
  unsigned short um[VEC], un[VEC], ux[VEC], us[VEC];
  #pragma unroll
  for (int v=0;v<VEC;v++){
    float pv = p[v];
    float sum_m = fmaf(degf, pv, sum[v]);
    float sq_m  = sq[v] + 2.f*pv*sum[v] + degf*pv*pv;
    float mean = sum_m*rdeg;
    float var = fmaxf(fmaf(sq_m, rdeg, -mean*mean), 0.f);
    float sd = sqrtf(var + 1e-5f);
    float mnv = deg>0 ? pv + mn[v] : 0.f;
    float mxv = deg>0 ? pv + mx[v] : 0.f;
    um[v]=f2bu(mean); un[v]=f2bu(mnv); ux[v]=f2bu(mxv); us[v]=f2bu(sd);
  }
  int t = c0 / F, f0 = c0 % F;
  bf16* base = agg + (size_t)n*4*NC + (size_t)t*4*F + f0;
  if constexpr (VEC==4){
    *(ushort4*)(base)       = make_ushort4(um[0],um[1],um[2],um[3]);
    *(ushort4*)(base + F)   = make_ushort4(un[0],un[1],un[2],un[3]);
    *(ushort4*)(base + 2*F) = make_ushort4(ux[0],ux[1],ux[2],ux[3]);
    *(ushort4*)(base + 3*F) = make_ushort4(us[0],us[1],us[2],us[3]);
  } else {
    *(ushort2*)(base)       = make_ushort2(um[0],um[1]);
    *(ushort2*)(base + F)   = make_ushort2(un[0],un[1]);
    *(ushort2*)(base + 2*F) = make_ushort2(ux[0],ux[1]);
    *(ushort2*)(base + 3*F) = make_ushort2(us[0],us[1]);
  }
  if (lane == 0){
    float dlog = logf(degc + 1.f);
    float avg = *avgp;
    scal[2*n]   = dlog/avg;
    scal[2*n+1] = avg/dlog;
  }
}

// ---------------- batch norm apply (stats accumulated by k_mgemm STATS) ----------------
template<typename TO, int C>
__global__ void k_bn_apply(const bf16* __restrict__ h, const float* __restrict__ stats,
     const float* __restrict__ g, const float* __restrict__ b,
     TO* __restrict__ out, int N){
  int idx = blockIdx.x*blockDim.x + threadIdx.x;   // quad index
  if (idx >= N*(C/4)) return;
  int c = (idx % (C/4))*4;
  float fn = (float)N;
  float v[4];
  ldbf<4>(h + (size_t)idx*4, v);
  float r[4];
  #pragma unroll
  for (int k = 0; k < 4; k++){
    float m = stats[c+k]/fn;
    float var = fmaxf(stats[C+c+k]/fn - m*m, 0.f);
    float inv = rsqrtf(var + 1e-5f);
    float vv = nanfix(v[k]);
    r[k] = fmaxf(g[c+k]*(vv - m)*inv + b[c+k], 0.f);
  }
  if constexpr (sizeof(TO) == 4){
    float4 o = {r[0], r[1], r[2], r[3]};
    *(float4*)((float*)out + (size_t)idx*4) = o;
  } else {
    ushort4 o = make_ushort4(f2bu(r[0]), f2bu(r[1]), f2bu(r[2]), f2bu(r[3]));
    *(ushort4*)((bf16*)out + (size_t)idx*4) = o;
  }
}

static inline int cdiv(int a, int b){ return (a + b - 1)/b; }

extern "C" void kernel_launch(void* const* d_in, const int* in_sizes, int n_in,
                              void* d_out, int out_size, void* d_ws, size_t ws_size,
                              hipStream_t stream){
  const int IN = 128, HID = 256, T = 4, F1 = 64, F2 = 32;
  const int N = in_sizes[0]/IN;
  const int E = in_sizes[1]/2;
  const int NC1 = T*F1;        // 256
  const int NC2 = T*F2;        // 128
  const int LDQ1 = 2*NC1 + NC1;   // 768: [P|Q|postX]
  const int LDQ2 = 2*NC2 + NC2;   // 384

  const float* x      = (const float*)d_in[0];
  const int*   ei     = (const int*)  d_in[1];
  const int*   srcE   = ei;
  const int*   tgtE   = ei + E;
  const float* avgp   = (const float*)d_in[2];
  const float* pre1W  = (const float*)d_in[3];
  const float* pre1b  = (const float*)d_in[4];
  const float* post1W = (const float*)d_in[5];
  const float* post1b = (const float*)d_in[6];
  const float* lin1W  = (const float*)d_in[7];
  const float* lin1b  = (const float*)d_in[8];
  const float* bn1g   = (const float*)d_in[9];
  const float* bn1b   = (const float*)d_in[10];
  const float* pre2W  = (const float*)d_in[11];
  const float* pre2b  = (const float*)d_in[12];
  const float* post2W = (const float*)d_in[13];
  const float* post2b = (const float*)d_in[14];
  const float* lin2W  = (const float*)d_in[15];
  const float* lin2b  = (const float*)d_in[16];
  const float* bn2g   = (const float*)d_in[17];
  const float* bn2b   = (const float*)d_in[18];

  // ---- workspace carve ----
  char* w = (char*)d_ws;
  auto alloc = [&](size_t bytes)->void*{
    void* p = (void*)w; w += (bytes + 255) & ~(size_t)255; return p;
  };
  // combined B^T for pre-GEMM: [WpqT (2*NC rows) | WxT (NC rows)], contiguous
  bf16* BT1    = (bf16*)alloc((size_t)LDQ1*IN*2);
  bf16* WpqT1  = BT1;              bf16* WxT1 = BT1 + (size_t)2*NC1*IN;
  float* bias1 = (float*)alloc((size_t)LDQ1*4);
  float* bpq1  = bias1;            float* bpost1 = bias1 + 2*NC1;
  bf16* Wagg31 = (bf16*)alloc((size_t)T*3*F1*4*F1*2);
  bf16* lin1WT = (bf16*)alloc((size_t)HID*NC1*2);
  bf16* BT2    = (bf16*)alloc((size_t)LDQ2*HID*2);
  bf16* WpqT2  = BT2;              bf16* WxT2 = BT2 + (size_t)2*NC2*HID;
  float* bias2 = (float*)alloc((size_t)LDQ2*4);
  float* bpq2  = bias2;            float* bpost2 = bias2 + 2*NC2;
  bf16* Wagg32 = (bf16*)alloc((size_t)T*3*F2*4*F2*2);
  bf16* lin2WT = (bf16*)alloc((size_t)128*NC2*2);
  // zero region: deg_i | cnt | stats (one memset)
  int* deg_i   = (int*)alloc((size_t)N*4);
  int* cnt     = (int*)alloc((size_t)N*4);
  float* stats = (float*)alloc(1024*4);
  size_t zbytes = (size_t)((char*)stats - (char*)deg_i) + 1024*4;
  int* offs    = (int*)alloc((size_t)(N+1)*4);
  int* bsum    = (int*)alloc((size_t)cdiv(N,256)*4);
  int* ssrc    = (int*)alloc((size_t)E*4);
  bf16* x_bf   = (bf16*)alloc((size_t)N*IN*2);
  bf16* PQX    = (bf16*)alloc((size_t)N*LDQ1*2);   // L2 reuses prefix [N, LDQ2]
  bf16* aggb   = (bf16*)alloc((size_t)N*4*NC1*2);  // L2 reuses prefix [N, 4*NC2]
  float* scal  = (float*)alloc((size_t)N*2*4);
  bf16* postbb = (bf16*)alloc((size_t)N*256*2);
  bf16* hpre   = (bf16*)alloc((size_t)N*256*2);
  bf16* h1b    = (bf16*)alloc((size_t)N*256*2);
  int NB = cdiv(N,64);

  hipMemsetAsync(deg_i, 0, zbytes, stream);

  // ---- setup: all weight repacks + x conversion + degree count (one dispatch) ----
  int sgx = cdiv(T*3*F1*4*F1, 256);   // 768 blocks covers the largest segment
  SetupArgs sa = { pre1W, pre1b, post1W, post1b, lin1W,
                   pre2W, pre2b, post2W, post2b, lin2W,
                   x, tgtE,
                   WpqT1, WxT1, Wagg31, lin1WT,
                   WpqT2, WxT2, Wagg32, lin2WT,
                   x_bf, deg_i,
                   bpq1, bpost1, bpq2, bpost2,
                   N*IN/4, E, sgx*256 };
  k_setup<<<dim3(sgx, 10),256,0,stream>>>(sa);

  // ---- counting sort of edges by target (parallel scan) ----
  int NBs = cdiv(N,256);
  k_scan1<<<NBs,256,0,stream>>>(deg_i, bsum, N);
  k_scan2<<<1,1024,0,stream>>>(bsum, NBs);
  k_scan3<<<NBs,256,0,stream>>>(deg_i, bsum, offs, N);
  k_scatter<<<cdiv(E,256),256,0,stream>>>(srcE, tgtE, offs, cnt, ssrc, E);

  // ================= Layer 1 =================
  k_mgemm<bf16,false><<<dim3(LDQ1/64,NB),256,0,stream>>>(x_bf, IN, BT1, bias1, PQX, LDQ1, N, IN, LDQ1, nullptr);
  k_agg<256,64,768><<<cdiv(N,4),256,0,stream>>>(PQX, ssrc, offs, avgp, aggb, scal, N);
  k_postagg<64><<<dim3(1,NB,T),256,0,stream>>>(aggb, Wagg31, PQX, LDQ1, 2*NC1, scal,
                                               postbb, NC1, N);
  k_mgemm<bf16,true><<<dim3(4,NB),256,0,stream>>>(postbb, NC1, lin1WT, lin1b, hpre, HID, N, NC1, HID, stats);
  k_bn_apply<bf16,256><<<cdiv(N*64,256),256,0,stream>>>(hpre, stats, bn1g, bn1b, h1b, N);

  // ================= Layer 2 =================
  k_mgemm<bf16,false><<<dim3(LDQ2/64,NB),256,0,stream>>>(h1b, HID, BT2, bias2, PQX, LDQ2, N, HID, LDQ2, nullptr);
  k_agg<128,32,384><<<cdiv(N,4),256,0,stream>>>(PQX, ssrc, offs, avgp, aggb, scal, N);
  k_postagg<32><<<dim3(1,NB,T),256,0,stream>>>(aggb, Wagg32, PQX, LDQ2, 2*NC2, scal,
                                               postbb, NC2, N);
  k_mgemm<bf16,true><<<dim3(2,NB),256,0,stream>>>(postbb, NC2, lin2WT, lin2b, hpre, 128, N, NC2, 128, stats + 512);
  k_bn_apply<float,128><<<cdiv(N*32,256),256,0,stream>>>(hpre, stats + 512, bn2g, bn2b, (float*)d_out, N);
}